// Round 5
// baseline (365.257 us; speedup 1.0000x reference)
//
#include <hip/hip_runtime.h>

// BahdanauAttention_83476984365343
//
// Reference: score is [B,T,1]; softmax over the size-1 last axis is
// identically 1.0, so  context[b,d] = sum_t keys[b,t,d].
// query/Ws/Wh/W/tanh are all dead code.
//
// B=32, T=4096, D=512. keys = largest input [B,T,D]. OUTPUT IS FP32
// (round-4 post-mortem: bf16-packed writes read back as fp32 gave absmax
// 374 = |ref[k]-ref[2k+1]| statistics — harness reads d_out as float32).
// Input dtype (fp32 vs bf16-packed) is sniffed on-device from bit patterns,
// wave-uniformly, since the harness may or may not bf16-ify inputs.
//
// Grid: (8 column-tiles, 32 batches) = 256 blocks; block 512 = 8 waves.

#define BB 32
#define TT 4096
#define DD 512

__global__ void BahdanauAttention_83476984365343_kernel(
    const unsigned int* __restrict__ keys_raw, float* __restrict__ out) {
  const int dt = (int)blockIdx.x;    // 0..7  column tile (64 cols)
  const int b = (int)blockIdx.y;     // 0..31 batch
  const int tid = (int)threadIdx.x;  // 0..511

  // ---- dtype sniff (wave-uniform; every wave reads the same 64 words) ----
  // bf16-packed: bits 14:7 of each uint are the LOW element's bf16 exponent
  // (~[117,129] for N(0,1) -> nearly all in [100,140]).
  // fp32 N(0,1): bits 14:7 are middle mantissa bits (uniform; P(in range)~0.16).
  const unsigned int w0 = keys_raw[tid & 63];
  const unsigned int e_lo = (w0 >> 7) & 0xffu;
  const bool plaus = (e_lo >= 100u) && (e_lo <= 140u);
  const unsigned long long mask = __ballot(plaus);
  const bool is_bf16 = (__popcll(mask) >= 48);

  __shared__ float smem[64][64];   // 16 KiB (fp32 path uses rows 0..31)
  __shared__ float smem2[8][64];   // 2 KiB

  if (!is_bf16) {
    // ---- fp32 path: float4 loads (16 B/lane) ----
    const int vec = tid & 15;  // which 16B of the 256B row segment
    const int r = tid >> 4;    // 0..31; strides by 32 over T
    const float4* kp = (const float4*)((const float*)keys_raw +
                                       (size_t)b * TT * DD + (size_t)dt * 64);
    float a0 = 0.f, a1 = 0.f, a2 = 0.f, a3 = 0.f;
#pragma unroll 4
    for (int t = r; t < TT; t += 32) {
      float4 v = kp[(size_t)t * (DD / 4) + vec];
      a0 += v.x; a1 += v.y; a2 += v.z; a3 += v.w;
    }
    float* row = &smem[r][vec * 4];
    row[0] = a0; row[1] = a1; row[2] = a2; row[3] = a3;
    __syncthreads();
    {  // fold 32 row-groups -> 8
      const int c = tid & 63;
      const int g = tid >> 6;  // 0..7
      float s = 0.f;
#pragma unroll
      for (int k = 0; k < 4; ++k) s += smem[g * 4 + k][c];
      smem2[g][c] = s;
    }
    __syncthreads();
  } else {
    // ---- bf16 path: uint4 loads (8 bf16 / 16 B per lane) ----
    const int vec = tid & 7;  // which 16B of the 128B row segment
    const int r = tid >> 3;   // 0..63; strides by 64 over T
    const uint4* kp =
        (const uint4*)(keys_raw + ((size_t)b * TT * DD + (size_t)dt * 64) / 2);
    float a0 = 0.f, a1 = 0.f, a2 = 0.f, a3 = 0.f;
    float a4 = 0.f, a5 = 0.f, a6 = 0.f, a7 = 0.f;
#pragma unroll 4
    for (int t = r; t < TT; t += 64) {
      uint4 v = kp[(size_t)t * (DD / 8) + vec];
      // little-endian: element 2k is the LOW 16 bits of word k;
      // bf16 value bits are the high 16 of an fp32.
      a0 += __uint_as_float(v.x << 16);
      a1 += __uint_as_float(v.x & 0xffff0000u);
      a2 += __uint_as_float(v.y << 16);
      a3 += __uint_as_float(v.y & 0xffff0000u);
      a4 += __uint_as_float(v.z << 16);
      a5 += __uint_as_float(v.z & 0xffff0000u);
      a6 += __uint_as_float(v.w << 16);
      a7 += __uint_as_float(v.w & 0xffff0000u);
    }
    float* row = &smem[r][vec * 8];
    row[0] = a0; row[1] = a1; row[2] = a2; row[3] = a3;
    row[4] = a4; row[5] = a5; row[6] = a6; row[7] = a7;
    __syncthreads();
    {  // fold 64 row-groups -> 8
      const int c = tid & 63;
      const int g = tid >> 6;  // 0..7
      float s = 0.f;
#pragma unroll
      for (int k = 0; k < 8; ++k) s += smem[g * 8 + k][c];
      smem2[g][c] = s;
    }
    __syncthreads();
  }

  // ---- epilogue: 64 threads fold 8 -> 1, store FP32 ----
  if (tid < 64) {
    float s = 0.f;
#pragma unroll
    for (int k = 0; k < 8; ++k) s += smem2[k][tid];
    out[(size_t)b * DD + dt * 64 + tid] = s;
  }
}

extern "C" void kernel_launch(void* const* d_in, const int* in_sizes, int n_in,
                              void* d_out, int out_size, void* d_ws, size_t ws_size,
                              hipStream_t stream) {
  // keys is by far the largest input (32*4096*512 = 67,108,864 elements);
  // locate it by size rather than trusting dict position.
  int ki = 0;
  for (int i = 1; i < n_in; ++i) {
    if (in_sizes[i] > in_sizes[ki]) ki = i;
  }
  const unsigned int* keys_raw = (const unsigned int*)d_in[ki];
  float* out = (float*)d_out;

  dim3 grid(8, BB);  // 256 blocks, one per (column-tile, batch)
  BahdanauAttention_83476984365343_kernel<<<grid, 512, 0, stream>>>(keys_raw,
                                                                    out);
}